// Round 1
// baseline (190.770 us; speedup 1.0000x reference)
//
#include <hip/hip_runtime.h>
#include <hip/hip_bf16.h>
#include <cstdint>
#include <cstddef>

// ---------- types ----------
typedef __attribute__((ext_vector_type(8))) _Float16 half8;
typedef __attribute__((ext_vector_type(4))) _Float16 half4v;
typedef __attribute__((ext_vector_type(4))) float floatx4;

#define MFMA16(a, b, c) __builtin_amdgcn_mfma_f32_16x16x32_f16((a), (b), (c), 0, 0, 0)

// Problem constants
// A=64, T=512, D=256, H=4, HD=64
#define NFEAT 8388608   // 64*512*256
#define NW    65536     // 256*256

// ---------- fp32 -> fp16 convert (features + 4 weight matrices) ----------
__global__ __launch_bounds__(256) void convert_kernel(
    const float* __restrict__ feat, const float* __restrict__ wq,
    const float* __restrict__ wk, const float* __restrict__ wv,
    const float* __restrict__ wo, _Float16* __restrict__ out)
{
    long tid  = (long)blockIdx.x * blockDim.x + threadIdx.x;
    long base = tid * 4;
    if (base >= (long)NFEAT + 4L * NW) return;
    const float* src;
    long off;
    if (base < NFEAT) { src = feat; off = base; }
    else {
        long r = base - NFEAT;
        int  w = (int)(r >> 16);          // 65536 per weight
        off = r & (NW - 1);
        src = (w == 0) ? wq : (w == 1) ? wk : (w == 2) ? wv : wo;
    }
    float4 v = *(const float4*)(src + off);
    half4v h = { (_Float16)v.x, (_Float16)v.y, (_Float16)v.z, (_Float16)v.w };
    *(half4v*)(out + base) = h;
}

// ---------- NT GEMM core: C[M x 256] = X[M x 256] * W[256 x 256]^T + bias ----------
// block tile 128(M) x 64(N), BK=32, 256 threads = 4 waves in 2x2
template <bool OUT_HALF>
__device__ __forceinline__ void gemm_core(
    const _Float16* __restrict__ X, const _Float16* __restrict__ W,
    const float* __restrict__ bias, void* __restrict__ Cptr)
{
    __shared__ _Float16 Xs[128 * 40];   // stride 40 (pad 8): 80B = 20 banks, 2-way max
    __shared__ _Float16 Wsm[64 * 40];

    const int tid  = threadIdx.x;
    const int lane = tid & 63, wid = tid >> 6;
    const int quad = lane >> 4, l16 = lane & 15;
    const int wm = wid & 1, wn = wid >> 1;       // wave tile: 64(M) x 32(N)
    const int bm = blockIdx.x, bn = blockIdx.y;

    floatx4 acc[4][2] = {};

    const _Float16* Xg = X + (size_t)bm * 128 * 256;
    const _Float16* Wg = W + (size_t)bn * 64 * 256;

    for (int k0 = 0; k0 < 256; k0 += 32) {
        // stage X tile 128x32 (2 chunks of 8 halfs per thread)
#pragma unroll
        for (int i = 0; i < 2; ++i) {
            int c = tid + 256 * i;
            int row = c >> 2, col = (c & 3) * 8;
            *(half8*)(&Xs[row * 40 + col]) =
                *(const half8*)(Xg + (size_t)row * 256 + k0 + col);
        }
        // stage W tile 64x32 (1 chunk per thread)
        {
            int row = tid >> 2, col = (tid & 3) * 8;
            *(half8*)(&Wsm[row * 40 + col]) =
                *(const half8*)(Wg + (size_t)row * 256 + k0 + col);
        }
        __syncthreads();

        half8 af[4], bf[2];
#pragma unroll
        for (int mi = 0; mi < 4; ++mi)
            af[mi] = *(const half8*)(&Xs[(wm * 64 + mi * 16 + l16) * 40 + quad * 8]);
#pragma unroll
        for (int ni = 0; ni < 2; ++ni)
            bf[ni] = *(const half8*)(&Wsm[(wn * 32 + ni * 16 + l16) * 40 + quad * 8]);
#pragma unroll
        for (int mi = 0; mi < 4; ++mi)
#pragma unroll
            for (int ni = 0; ni < 2; ++ni)
                acc[mi][ni] = MFMA16(af[mi], bf[ni], acc[mi][ni]);
        __syncthreads();
    }

    // epilogue: C/D layout col = lane&15, row = quad*4 + r
#pragma unroll
    for (int ni = 0; ni < 2; ++ni) {
        int col = bn * 64 + wn * 32 + ni * 16 + l16;
        float bv = bias[col];
#pragma unroll
        for (int mi = 0; mi < 4; ++mi) {
#pragma unroll
            for (int r = 0; r < 4; ++r) {
                int row = bm * 128 + wm * 64 + mi * 16 + quad * 4 + r;
                float v = acc[mi][ni][r] + bv;
                if (OUT_HALF)
                    ((_Float16*)Cptr)[(size_t)row * 256 + col] = (_Float16)v;
                else
                    ((float*)Cptr)[(size_t)row * 256 + col] = v;
            }
        }
    }
}

__global__ __launch_bounds__(256) void qkv_gemm(
    const _Float16* __restrict__ featH, const _Float16* __restrict__ WH,
    const float* __restrict__ bq, const float* __restrict__ bk,
    const float* __restrict__ bv,
    _Float16* __restrict__ Qb, _Float16* __restrict__ Kb, _Float16* __restrict__ Vb)
{
    int z = blockIdx.z;
    const _Float16* W = WH + (size_t)z * NW;  // wq, wk, wv consecutive
    const float* bias = (z == 0) ? bq : (z == 1) ? bk : bv;
    _Float16* out    = (z == 0) ? Qb : (z == 1) ? Kb : Vb;
    gemm_core<true>(featH, W, bias, out);
}

__global__ __launch_bounds__(256) void out_gemm(
    const _Float16* __restrict__ attnH, const _Float16* __restrict__ WoH,
    const float* __restrict__ bo, float* __restrict__ out)
{
    gemm_core<false>(attnH, WoH, bo, out);
}

// ---------- banded sparse attention ----------
// grid: x = qtile (0..7, 64 q rows each), y = head (0..3), z = animal (0..63)
// key band: s in [q0-64, q0+127] (width 192) covers |t-s|<=64 for all rows in tile
__global__ __launch_bounds__(256) void attn_kernel(
    const _Float16* __restrict__ Qb, const _Float16* __restrict__ Kb,
    const _Float16* __restrict__ Vb, const float* __restrict__ positions,
    const int* __restrict__ mdp, const int* __restrict__ twp,
    _Float16* __restrict__ attnb)
{
    const int qt = blockIdx.x, h = blockIdx.y, a = blockIdx.z;
    const int q0 = qt * 64;
    const int s_base = q0 - 64;
    const int tid = threadIdx.x, lane = tid & 63, wid = tid >> 6;
    const int quad = lane >> 4, l16 = lane & 15;

    // LDS: Ks [192][72] (27648 B) reused later as Ps [4 waves][16][200] (25600 B)
    __shared__ _Float16 KPs[192 * 72];
    __shared__ _Float16 Vt[64 * 200];      // V transposed: [d][key], stride 200
    __shared__ float qpos_s[128];          // 64 q rows * (x,y)
    __shared__ float kpos_s[384];          // 192 keys * (x,y)

    const size_t abase = (size_t)a * 512;

    // ---- stage K band: rows s_idx 0..191, 64 halfs each ----
#pragma unroll
    for (int i = 0; i < 6; ++i) {
        int c  = tid + 256 * i;            // 1536 chunks of 8 halfs
        int si = c >> 3, col = (c & 7) * 8;
        int sr = s_base + si;
        int sc = min(max(sr, 0), 511);     // clamp; invalid keys masked later
        *(half8*)(&KPs[si * 72 + col]) =
            *(const half8*)(Kb + (abase + sc) * 256 + h * 64 + col);
    }
    // ---- stage V transposed ----
#pragma unroll
    for (int i = 0; i < 6; ++i) {
        int c  = tid + 256 * i;
        int si = c >> 3, d0 = (c & 7) * 8;
        int sc = min(max(s_base + si, 0), 511);
        half8 v = *(const half8*)(Vb + (abase + sc) * 256 + h * 64 + d0);
#pragma unroll
        for (int j = 0; j < 8; ++j) Vt[(d0 + j) * 200 + si] = v[j];
    }
    // ---- stage positions ----
    if (tid < 128)
        qpos_s[tid] = positions[(abase + q0 + (tid >> 1)) * 2 + (tid & 1)];
    for (int i = tid; i < 384; i += 256) {
        int si = i >> 1;
        int sc = min(max(s_base + si, 0), 511);
        kpos_s[i] = positions[(abase + sc) * 2 + (i & 1)];
    }
    __syncthreads();

    const int md = *mdp, tw = *twp;
    const float md2 = (float)(md * md);

    // ---- per-wave: 16 q rows ----
    const size_t qrow = abase + q0 + wid * 16 + l16;
    half8 aq0 = *(const half8*)(Qb + qrow * 256 + h * 64 + quad * 8);
    half8 aq1 = *(const half8*)(Qb + qrow * 256 + h * 64 + 32 + quad * 8);

    float qpx[4], qpy[4];
    int trow[4];
#pragma unroll
    for (int r = 0; r < 4; ++r) {
        int m = wid * 16 + quad * 4 + r;
        trow[r] = q0 + m;
        qpx[r] = qpos_s[m * 2];
        qpy[r] = qpos_s[m * 2 + 1];
    }

    // ---- S = Q K^T over 12 key tiles ----
    floatx4 S[12];
#pragma unroll
    for (int j = 0; j < 12; ++j) {
        half8 bk0 = *(const half8*)(&KPs[(j * 16 + l16) * 72 + quad * 8]);
        half8 bk1 = *(const half8*)(&KPs[(j * 16 + l16) * 72 + 32 + quad * 8]);
        floatx4 acc = {};
        acc = MFMA16(aq0, bk0, acc);
        acc = MFMA16(aq1, bk1, acc);
        int si = j * 16 + l16;
        int sr = s_base + si;
        float kx = kpos_s[si * 2], ky = kpos_s[si * 2 + 1];
        bool svalid = (sr >= 0) && (sr < 512);
#pragma unroll
        for (int r = 0; r < 4; ++r) {
            float dx = qpx[r] - kx, dy = qpy[r] - ky;
            float d2 = dx * dx + dy * dy;
            int dt = trow[r] - sr; dt = dt < 0 ? -dt : dt;
            bool ok = svalid && (d2 <= md2) && (dt <= tw);
            S[j][r] = ok ? acc[r] * 0.125f : -1e30f;   // scale = 1/sqrt(64)
        }
    }

    // ---- softmax (exact, row max + sum via quad shuffles) ----
    float minv[4];
#pragma unroll
    for (int r = 0; r < 4; ++r) {
        float m = -1e30f;
#pragma unroll
        for (int j = 0; j < 12; ++j) m = fmaxf(m, S[j][r]);
        m = fmaxf(m, __shfl_xor(m, 1));
        m = fmaxf(m, __shfl_xor(m, 2));
        m = fmaxf(m, __shfl_xor(m, 4));
        m = fmaxf(m, __shfl_xor(m, 8));
        float l = 0.f;
#pragma unroll
        for (int j = 0; j < 12; ++j) {
            float p = __expf(S[j][r] - m);
            S[j][r] = p;
            l += p;
        }
        l += __shfl_xor(l, 1);
        l += __shfl_xor(l, 2);
        l += __shfl_xor(l, 4);
        l += __shfl_xor(l, 8);
        minv[r] = 1.0f / l;
    }

    __syncthreads();   // all waves done reading Ks before Ps overwrites it

    // ---- write P (normalized) into A-operand layout: row-major [16][200] per wave ----
    _Float16* Ps = KPs + wid * 16 * 200;
#pragma unroll
    for (int j = 0; j < 12; ++j)
#pragma unroll
        for (int r = 0; r < 4; ++r)
            Ps[(quad * 4 + r) * 200 + j * 16 + l16] = (_Float16)(S[j][r] * minv[r]);

    // ---- O = P V : M=16, K=192 (6 steps), N=64 (4 tiles) ----
    half8 af[6];
#pragma unroll
    for (int k = 0; k < 6; ++k)
        af[k] = *(const half8*)(&Ps[l16 * 200 + k * 32 + quad * 8]);
#pragma unroll
    for (int n = 0; n < 4; ++n) {
        floatx4 accO = {};
#pragma unroll
        for (int k = 0; k < 6; ++k) {
            half8 bv = *(const half8*)(&Vt[(n * 16 + l16) * 200 + k * 32 + quad * 8]);
            accO = MFMA16(af[k], bv, accO);
        }
#pragma unroll
        for (int r = 0; r < 4; ++r) {
            int row = q0 + wid * 16 + quad * 4 + r;
            attnb[(abase + row) * 256 + h * 64 + n * 16 + l16] = (_Float16)accO[r];
        }
    }
}

// ---------- launch ----------
extern "C" void kernel_launch(void* const* d_in, const int* in_sizes, int n_in,
                              void* d_out, int out_size, void* d_ws, size_t ws_size,
                              hipStream_t stream)
{
    const float* feat = (const float*)d_in[0];
    const float* pos  = (const float*)d_in[1];
    const float* Wq   = (const float*)d_in[2];
    const float* bq   = (const float*)d_in[3];
    const float* Wk   = (const float*)d_in[4];
    const float* bk   = (const float*)d_in[5];
    const float* Wv   = (const float*)d_in[6];
    const float* bv   = (const float*)d_in[7];
    const float* Wo   = (const float*)d_in[8];
    const float* bo   = (const float*)d_in[9];
    const int*   md   = (const int*)d_in[10];
    const int*   tw   = (const int*)d_in[11];
    float*       out  = (float*)d_out;

    _Float16* ws    = (_Float16*)d_ws;
    _Float16* featH = ws;                      // NFEAT halfs (also reused as attnH)
    _Float16* WH    = featH + NFEAT;           // 4*NW halfs: wq, wk, wv, wo
    _Float16* Qb    = WH + 4 * NW;
    _Float16* Kb    = Qb + NFEAT;
    _Float16* Vb    = Kb + NFEAT;
    _Float16* attnH = featH;                   // features dead after qkv_gemm
    // total: 4*NFEAT + 4*NW halfs = ~67.6 MB of d_ws

    convert_kernel<<<8448, 256, 0, stream>>>(feat, Wq, Wk, Wv, Wo, ws);

    dim3 gqkv(256, 4, 3);
    qkv_gemm<<<gqkv, 256, 0, stream>>>(featH, WH, bq, bk, bv, Qb, Kb, Vb);

    dim3 gattn(8, 4, 64);
    attn_kernel<<<gattn, 256, 0, stream>>>(Qb, Kb, Vb, pos, md, tw, attnH);

    dim3 gout(256, 4, 1);
    out_gemm<<<gout, 256, 0, stream>>>(attnH, WH + 3 * (size_t)NW, bo, out);
}

// Round 2
// 187.475 us; speedup vs baseline: 1.0176x; 1.0176x over previous
//
#include <hip/hip_runtime.h>
#include <hip/hip_bf16.h>
#include <cstdint>
#include <cstddef>

// ---------- types ----------
typedef __attribute__((ext_vector_type(8))) _Float16 half8;
typedef __attribute__((ext_vector_type(4))) _Float16 half4v;
typedef __attribute__((ext_vector_type(4))) float floatx4;

#define MFMA16(a, b, c) __builtin_amdgcn_mfma_f32_16x16x32_f16((a), (b), (c), 0, 0, 0)

// Problem constants: A=64, T=512, D=256, H=4, HD=64
#define NFEAT 8388608   // 64*512*256
#define NW    65536     // 256*256

// ---------- fp32 -> fp16 convert (features + 4 weight matrices) ----------
__global__ __launch_bounds__(256) void convert_kernel(
    const float* __restrict__ feat, const float* __restrict__ wq,
    const float* __restrict__ wk, const float* __restrict__ wv,
    const float* __restrict__ wo, _Float16* __restrict__ out)
{
    long tid  = (long)blockIdx.x * blockDim.x + threadIdx.x;
    long base = tid * 4;
    if (base >= (long)NFEAT + 4L * NW) return;
    const float* src;
    long off;
    if (base < NFEAT) { src = feat; off = base; }
    else {
        long r = base - NFEAT;
        int  w = (int)(r >> 16);
        off = r & (NW - 1);
        src = (w == 0) ? wq : (w == 1) ? wk : (w == 2) ? wv : wo;
    }
    float4 v = *(const float4*)(src + off);
    half4v h = { (_Float16)v.x, (_Float16)v.y, (_Float16)v.z, (_Float16)v.w };
    *(half4v*)(out + base) = h;
}

// ---------- NT GEMM: C[128 x 256] = X[128 x 256] * W[256 x 256]^T + bias ----------
// full-N block tile: each X tile staged once per weight matrix (vs 4x before).
// 256 threads = 4 waves, wave tile 64(M) x 128(N), acc[4][8]
template <bool OUT_HALF>
__device__ __forceinline__ void gemm_core2(
    const _Float16* __restrict__ X, const _Float16* __restrict__ W,
    const float* __restrict__ bias, void* __restrict__ Cptr, int bm)
{
    __shared__ _Float16 Xs[128 * 40];   // pad 8: 80B stride = 20 banks
    __shared__ _Float16 Ws[256 * 40];

    const int tid  = threadIdx.x;
    const int lane = tid & 63, wid = tid >> 6;
    const int quad = lane >> 4, l16 = lane & 15;
    const int wm = wid & 1, wn = wid >> 1;       // wave tile: 64(M) x 128(N)

    floatx4 acc[4][8] = {};
    const _Float16* Xg = X + (size_t)bm * 128 * 256;

    for (int k0 = 0; k0 < 256; k0 += 32) {
        // stage X tile 128x32
#pragma unroll
        for (int i = 0; i < 2; ++i) {
            int c = tid + 256 * i;
            int row = c >> 2, col = (c & 3) * 8;
            *(half8*)(&Xs[row * 40 + col]) =
                *(const half8*)(Xg + (size_t)row * 256 + k0 + col);
        }
        // stage W tile 256x32
#pragma unroll
        for (int i = 0; i < 4; ++i) {
            int c = tid + 256 * i;
            int row = c >> 2, col = (c & 3) * 8;
            *(half8*)(&Ws[row * 40 + col]) =
                *(const half8*)(W + (size_t)row * 256 + k0 + col);
        }
        __syncthreads();

        half8 af[4], bf[8];
#pragma unroll
        for (int mi = 0; mi < 4; ++mi)
            af[mi] = *(const half8*)(&Xs[(wm * 64 + mi * 16 + l16) * 40 + quad * 8]);
#pragma unroll
        for (int ni = 0; ni < 8; ++ni)
            bf[ni] = *(const half8*)(&Ws[(wn * 128 + ni * 16 + l16) * 40 + quad * 8]);
#pragma unroll
        for (int mi = 0; mi < 4; ++mi)
#pragma unroll
            for (int ni = 0; ni < 8; ++ni)
                acc[mi][ni] = MFMA16(af[mi], bf[ni], acc[mi][ni]);
        __syncthreads();
    }

    // epilogue: C/D layout col = lane&15, row = quad*4 + r
#pragma unroll
    for (int ni = 0; ni < 8; ++ni) {
        int col = wn * 128 + ni * 16 + l16;
        float bv = bias[col];
#pragma unroll
        for (int mi = 0; mi < 4; ++mi) {
#pragma unroll
            for (int r = 0; r < 4; ++r) {
                int row = bm * 128 + wm * 64 + mi * 16 + quad * 4 + r;
                float v = acc[mi][ni][r] + bv;
                if (OUT_HALF)
                    ((_Float16*)Cptr)[(size_t)row * 256 + col] = (_Float16)v;
                else
                    ((float*)Cptr)[(size_t)row * 256 + col] = v;
            }
        }
    }
}

// grid: x = z (0..2, fastest -> 3 blocks sharing X tile run adjacently), y = bm
__global__ __launch_bounds__(256, 2) void qkv_gemm(
    const _Float16* __restrict__ featH, const _Float16* __restrict__ WH,
    const float* __restrict__ bq, const float* __restrict__ bk,
    const float* __restrict__ bv,
    _Float16* __restrict__ Qb, _Float16* __restrict__ Kb, _Float16* __restrict__ Vb)
{
    int z = blockIdx.x;
    const _Float16* W = WH + (size_t)z * NW;
    const float* bias = (z == 0) ? bq : (z == 1) ? bk : bv;
    _Float16* out    = (z == 0) ? Qb : (z == 1) ? Kb : Vb;
    gemm_core2<true>(featH, W, bias, out, blockIdx.y);
}

__global__ __launch_bounds__(256, 2) void out_gemm(
    const _Float16* __restrict__ attnH, const _Float16* __restrict__ WoH,
    const float* __restrict__ bo, float* __restrict__ out)
{
    gemm_core2<false>(attnH, WoH, bo, out, blockIdx.y);
}

// ---------- banded sparse attention ----------
// grid: x = qtile (0..7, 64 q rows each), y = head (0..3), z = animal (0..63)
// key band: s in [q0-64, q0+127] (width 192) covers |t-s|<=64 for all rows in tile
__global__ __launch_bounds__(256) void attn_kernel(
    const _Float16* __restrict__ Qb, const _Float16* __restrict__ Kb,
    const _Float16* __restrict__ Vb, const float* __restrict__ positions,
    const int* __restrict__ mdp, const int* __restrict__ twp,
    _Float16* __restrict__ attnb)
{
    const int qt = blockIdx.x, h = blockIdx.y, a = blockIdx.z;
    const int q0 = qt * 64;
    const int s_base = q0 - 64;
    const int tid = threadIdx.x, lane = tid & 63, wid = tid >> 6;
    const int quad = lane >> 4, l16 = lane & 15;

    // LDS 53.2 KB -> 3 blocks/CU
    __shared__ _Float16 KPs[192 * 72];     // K band; reused as P [4][16][200]
    __shared__ _Float16 Vt[64 * 200];      // V transposed: [d][key]

    const size_t abase = (size_t)a * 512;

    // ---- stage K band (8 lanes per row, coalesced, conflict-free) ----
#pragma unroll
    for (int i = 0; i < 6; ++i) {
        int c  = tid + 256 * i;
        int si = c >> 3, col = (c & 7) * 8;
        int sc = min(max(s_base + si, 0), 511);
        *(half8*)(&KPs[si * 72 + col]) =
            *(const half8*)(Kb + (abase + sc) * 256 + h * 64 + col);
    }
    // ---- stage V transposed: consecutive lanes -> consecutive si ----
    // (write addr = (d0+j)*200 + si: 64 lanes span 64 contiguous halfs = 32
    //  banks 2-way => free; old layout had 8-way same-bank conflicts)
#pragma unroll
    for (int i = 0; i < 6; ++i) {
        int c  = tid + 256 * i;           // 1536 chunks
        int si = c % 192;
        int d0 = (c / 192) * 8;
        int sc = min(max(s_base + si, 0), 511);
        half8 v = *(const half8*)(Vb + (abase + sc) * 256 + h * 64 + d0);
#pragma unroll
        for (int j = 0; j < 8; ++j) Vt[(d0 + j) * 200 + si] = v[j];
    }
    __syncthreads();

    const int md = *mdp, tw = *twp;
    const float md2 = (float)(md * md);

    // ---- per-wave: 16 q rows ----
    const size_t qrow = abase + q0 + wid * 16 + l16;
    half8 aq0 = *(const half8*)(Qb + qrow * 256 + h * 64 + quad * 8);
    half8 aq1 = *(const half8*)(Qb + qrow * 256 + h * 64 + 32 + quad * 8);

    float qpx[4], qpy[4];
    int trow[4];
#pragma unroll
    for (int r = 0; r < 4; ++r) {
        int m = wid * 16 + quad * 4 + r;
        trow[r] = q0 + m;
        float2 qp = *(const float2*)(positions + (abase + q0 + m) * 2);
        qpx[r] = qp.x;
        qpy[r] = qp.y;
    }

    // ---- S = Q K^T over 12 key tiles ----
    floatx4 S[12];
#pragma unroll
    for (int j = 0; j < 12; ++j) {
        half8 bk0 = *(const half8*)(&KPs[(j * 16 + l16) * 72 + quad * 8]);
        half8 bk1 = *(const half8*)(&KPs[(j * 16 + l16) * 72 + 32 + quad * 8]);
        floatx4 acc = {};
        acc = MFMA16(aq0, bk0, acc);
        acc = MFMA16(aq1, bk1, acc);
        int si = j * 16 + l16;
        int sr = s_base + si;
        int sc = min(max(sr, 0), 511);
        float2 kp = *(const float2*)(positions + (abase + sc) * 2);
        bool svalid = (sr >= 0) && (sr < 512);
#pragma unroll
        for (int r = 0; r < 4; ++r) {
            float dx = qpx[r] - kp.x, dy = qpy[r] - kp.y;
            float d2 = dx * dx + dy * dy;
            int dt = trow[r] - sr; dt = dt < 0 ? -dt : dt;
            bool ok = svalid && (d2 <= md2) && (dt <= tw);
            S[j][r] = ok ? acc[r] * 0.125f : -1e30f;   // scale = 1/sqrt(64)
        }
    }

    // ---- softmax (exact; quad shuffles reduce across the 16 key cols) ----
    float minv[4];
#pragma unroll
    for (int r = 0; r < 4; ++r) {
        float m = -1e30f;
#pragma unroll
        for (int j = 0; j < 12; ++j) m = fmaxf(m, S[j][r]);
        m = fmaxf(m, __shfl_xor(m, 1));
        m = fmaxf(m, __shfl_xor(m, 2));
        m = fmaxf(m, __shfl_xor(m, 4));
        m = fmaxf(m, __shfl_xor(m, 8));
        float l = 0.f;
#pragma unroll
        for (int j = 0; j < 12; ++j) {
            float p = __expf(S[j][r] - m);
            S[j][r] = p;
            l += p;
        }
        l += __shfl_xor(l, 1);
        l += __shfl_xor(l, 2);
        l += __shfl_xor(l, 4);
        l += __shfl_xor(l, 8);
        minv[r] = 1.0f / l;
    }

    __syncthreads();   // all waves done reading Ks before Ps overwrites it

    // ---- write P (normalized) into A-operand layout: row-major [16][200] per wave ----
    _Float16* Ps = KPs + wid * 16 * 200;
#pragma unroll
    for (int j = 0; j < 12; ++j)
#pragma unroll
        for (int r = 0; r < 4; ++r)
            Ps[(quad * 4 + r) * 200 + j * 16 + l16] = (_Float16)(S[j][r] * minv[r]);

    // ---- O = P V : M=16, K=192 (6 steps), N=64 (4 tiles) ----
    half8 af[6];
#pragma unroll
    for (int k = 0; k < 6; ++k)
        af[k] = *(const half8*)(&Ps[l16 * 200 + k * 32 + quad * 8]);
#pragma unroll
    for (int n = 0; n < 4; ++n) {
        floatx4 accO = {};
#pragma unroll
        for (int k = 0; k < 6; ++k) {
            half8 bv = *(const half8*)(&Vt[(n * 16 + l16) * 200 + k * 32 + quad * 8]);
            accO = MFMA16(af[k], bv, accO);
        }
#pragma unroll
        for (int r = 0; r < 4; ++r) {
            int row = q0 + wid * 16 + quad * 4 + r;
            attnb[(abase + row) * 256 + h * 64 + n * 16 + l16] = (_Float16)accO[r];
        }
    }
}

// ---------- launch ----------
extern "C" void kernel_launch(void* const* d_in, const int* in_sizes, int n_in,
                              void* d_out, int out_size, void* d_ws, size_t ws_size,
                              hipStream_t stream)
{
    const float* feat = (const float*)d_in[0];
    const float* pos  = (const float*)d_in[1];
    const float* Wq   = (const float*)d_in[2];
    const float* bq   = (const float*)d_in[3];
    const float* Wk   = (const float*)d_in[4];
    const float* bk   = (const float*)d_in[5];
    const float* Wv   = (const float*)d_in[6];
    const float* bv   = (const float*)d_in[7];
    const float* Wo   = (const float*)d_in[8];
    const float* bo   = (const float*)d_in[9];
    const int*   md   = (const int*)d_in[10];
    const int*   tw   = (const int*)d_in[11];
    float*       out  = (float*)d_out;

    _Float16* ws    = (_Float16*)d_ws;
    _Float16* featH = ws;                      // NFEAT halfs (reused as attnH)
    _Float16* WH    = featH + NFEAT;           // 4*NW halfs: wq, wk, wv, wo
    _Float16* Qb    = WH + 4 * NW;
    _Float16* Kb    = Qb + NFEAT;
    _Float16* Vb    = Kb + NFEAT;
    _Float16* attnH = featH;                   // features dead after qkv_gemm

    convert_kernel<<<8448, 256, 0, stream>>>(feat, Wq, Wk, Wv, Wo, ws);

    dim3 gqkv(3, 256);
    qkv_gemm<<<gqkv, 256, 0, stream>>>(featH, WH, bq, bk, bv, Qb, Kb, Vb);

    dim3 gattn(8, 4, 64);
    attn_kernel<<<gattn, 256, 0, stream>>>(Qb, Kb, Vb, pos, md, tw, attnH);

    dim3 gout(1, 256);
    out_gemm<<<gout, 256, 0, stream>>>(attnH, WH + 3 * (size_t)NW, bo, out);
}

// Round 3
// 183.645 us; speedup vs baseline: 1.0388x; 1.0209x over previous
//
#include <hip/hip_runtime.h>
#include <hip/hip_bf16.h>
#include <cstdint>
#include <cstddef>

// ---------- types ----------
typedef __attribute__((ext_vector_type(8))) _Float16 half8;
typedef __attribute__((ext_vector_type(4))) _Float16 half4v;
typedef __attribute__((ext_vector_type(4))) float floatx4;

#define MFMA16(a, b, c) __builtin_amdgcn_mfma_f32_16x16x32_f16((a), (b), (c), 0, 0, 0)

// direct global->LDS DMA, 16B per lane, dest = uniform base + lane*16
#define GLOAD_LDS16(g, l)                                                     \
    __builtin_amdgcn_global_load_lds(                                         \
        (const __attribute__((address_space(1))) void*)(g),                   \
        (__attribute__((address_space(3))) void*)(l), 16, 0, 0)

// Problem constants: A=64, T=512, D=256, H=4, HD=64
#define NFEAT 8388608   // 64*512*256
#define NW    65536     // 256*256

// ---------- fp32 -> fp16 convert (features + 4 weight matrices) ----------
__global__ __launch_bounds__(256) void convert_kernel(
    const float* __restrict__ feat, const float* __restrict__ wq,
    const float* __restrict__ wk, const float* __restrict__ wv,
    const float* __restrict__ wo, _Float16* __restrict__ out)
{
    long tid  = (long)blockIdx.x * blockDim.x + threadIdx.x;
    long base = tid * 4;
    if (base >= (long)NFEAT + 4L * NW) return;
    const float* src;
    long off;
    if (base < NFEAT) { src = feat; off = base; }
    else {
        long r = base - NFEAT;
        int  w = (int)(r >> 16);
        off = r & (NW - 1);
        src = (w == 0) ? wq : (w == 1) ? wk : (w == 2) ? wv : wo;
    }
    float4 v = *(const float4*)(src + off);
    half4v h = { (_Float16)v.x, (_Float16)v.y, (_Float16)v.z, (_Float16)v.w };
    *(half4v*)(out + base) = h;
}

// ---------- m97-style NT GEMM: C[128x128 tile] = X * W^T + bias ----------
// BM=BN=128, BK=64, 256 threads = 4 waves (2x2), wave tile 64x64 (4x4 frags).
// Staging: global_load_lds dwordx4 into PACKED LDS [128][64] with XOR chunk
// swizzle applied at the global source (chunk ^= row&7) so ds_read_b128
// fragment reads are 2-way-max bank-conflict free (2-way is free per m136).

// stage 128 rows x 64 halfs; src row stride 256 halfs
__device__ __forceinline__ void stage128x64(
    const _Float16* __restrict__ src, _Float16* __restrict__ lds,
    int wid, int lane)
{
#pragma unroll
    for (int i = 0; i < 4; ++i) {
        int grp = wid * 4 + i;             // 16 groups of 8 rows
        int row = grp * 8 + (lane >> 3);
        int sc  = (lane & 7) ^ (row & 7);  // source chunk for this dest slot
        GLOAD_LDS16(src + (size_t)row * 256 + sc * 8, lds + grp * 512);
    }
}

template <bool OUT_HALF>
__device__ __forceinline__ void gemm128x128(
    const _Float16* __restrict__ X, const _Float16* __restrict__ W,
    const float* __restrict__ bias, void* __restrict__ Cptr, int bm, int bn)
{
    __shared__ _Float16 As[128 * 64];   // packed, swizzled (32 KB total)
    __shared__ _Float16 Bs[128 * 64];

    const int tid  = threadIdx.x;
    const int lane = tid & 63, wid = tid >> 6;
    const int quad = lane >> 4, l16 = lane & 15;
    const int wm = wid & 1, wn = wid >> 1;

    floatx4 acc[4][4] = {};
    const _Float16* Xg = X + (size_t)bm * 128 * 256;
    const _Float16* Wg = W + (size_t)bn * 128 * 256;

    for (int k0 = 0; k0 < 256; k0 += 64) {
        stage128x64(Xg + k0, As, wid, lane);
        stage128x64(Wg + k0, Bs, wid, lane);
        __syncthreads();   // compiler emits vmcnt(0) drain for the DMA loads
#pragma unroll
        for (int kh = 0; kh < 2; ++kh) {
            half8 af[4], bf[4];
#pragma unroll
            for (int mi = 0; mi < 4; ++mi) {
                int row = wm * 64 + mi * 16 + l16;
                int ch  = (kh * 4 + quad) ^ (l16 & 7);
                af[mi] = *(const half8*)(&As[row * 64 + ch * 8]);
            }
#pragma unroll
            for (int ni = 0; ni < 4; ++ni) {
                int row = wn * 64 + ni * 16 + l16;
                int ch  = (kh * 4 + quad) ^ (l16 & 7);
                bf[ni] = *(const half8*)(&Bs[row * 64 + ch * 8]);
            }
#pragma unroll
            for (int mi = 0; mi < 4; ++mi)
#pragma unroll
                for (int ni = 0; ni < 4; ++ni)
                    acc[mi][ni] = MFMA16(af[mi], bf[ni], acc[mi][ni]);
        }
        __syncthreads();
    }

    // epilogue: C/D layout col = lane&15, row = quad*4 + r
#pragma unroll
    for (int ni = 0; ni < 4; ++ni) {
        int col = bn * 128 + wn * 64 + ni * 16 + l16;
        float bv = bias[col];
#pragma unroll
        for (int mi = 0; mi < 4; ++mi) {
#pragma unroll
            for (int r = 0; r < 4; ++r) {
                int row = bm * 128 + wm * 64 + mi * 16 + quad * 4 + r;
                float v = acc[mi][ni][r] + bv;
                if (OUT_HALF)
                    ((_Float16*)Cptr)[(size_t)row * 256 + col] = (_Float16)v;
                else
                    ((float*)Cptr)[(size_t)row * 256 + col] = v;
            }
        }
    }
}

// grid: x = z*2+bn (0..5, fastest -> blocks sharing X tile adjacent), y = bm
__global__ __launch_bounds__(256) void qkv_gemm(
    const _Float16* __restrict__ featH, const _Float16* __restrict__ WH,
    const float* __restrict__ bq, const float* __restrict__ bk,
    const float* __restrict__ bv,
    _Float16* __restrict__ Qb, _Float16* __restrict__ Kb, _Float16* __restrict__ Vb)
{
    int z = blockIdx.x >> 1, bn = blockIdx.x & 1;
    const _Float16* W = WH + (size_t)z * NW;
    const float* bias = (z == 0) ? bq : (z == 1) ? bk : bv;
    _Float16* out    = (z == 0) ? Qb : (z == 1) ? Kb : Vb;
    gemm128x128<true>(featH, W, bias, out, blockIdx.y, bn);
}

__global__ __launch_bounds__(256) void out_gemm(
    const _Float16* __restrict__ attnH, const _Float16* __restrict__ WoH,
    const float* __restrict__ bo, float* __restrict__ out)
{
    gemm128x128<false>(attnH, WoH, bo, out, blockIdx.y, blockIdx.x);
}

// ---------- banded sparse attention ----------
// grid: x = qtile (0..7, 64 q rows each), y = head (0..3), z = animal (0..63)
__global__ __launch_bounds__(256) void attn_kernel(
    const _Float16* __restrict__ Qb, const _Float16* __restrict__ Kb,
    const _Float16* __restrict__ Vb, const float* __restrict__ positions,
    const int* __restrict__ mdp, const int* __restrict__ twp,
    _Float16* __restrict__ attnb)
{
    const int qt = blockIdx.x, h = blockIdx.y, a = blockIdx.z;
    const int q0 = qt * 64;
    const int s_base = q0 - 64;
    const int tid = threadIdx.x, lane = tid & 63, wid = tid >> 6;
    const int quad = lane >> 4, l16 = lane & 15;

    __shared__ _Float16 KPs[192 * 72];     // K band; reused as P [4][16][200]
    __shared__ _Float16 Vt[64 * 200];      // V transposed: [d][key]

    const size_t abase = (size_t)a * 512;

    // ---- hoisted per-wave Q fragment + q-position loads (overlap staging) ----
    const size_t qrow = abase + q0 + wid * 16 + l16;
    half8 aq0 = *(const half8*)(Qb + qrow * 256 + h * 64 + quad * 8);
    half8 aq1 = *(const half8*)(Qb + qrow * 256 + h * 64 + 32 + quad * 8);
    float qpx[4], qpy[4];
    int trow[4];
#pragma unroll
    for (int r = 0; r < 4; ++r) {
        int m = wid * 16 + quad * 4 + r;
        trow[r] = q0 + m;
        float2 qp = *(const float2*)(positions + (abase + q0 + m) * 2);
        qpx[r] = qp.x;
        qpy[r] = qp.y;
    }

    // ---- stage K band ----
#pragma unroll
    for (int i = 0; i < 6; ++i) {
        int c  = tid + 256 * i;
        int si = c >> 3, col = (c & 7) * 8;
        int sc = min(max(s_base + si, 0), 511);
        *(half8*)(&KPs[si * 72 + col]) =
            *(const half8*)(Kb + (abase + sc) * 256 + h * 64 + col);
    }
    // ---- stage V transposed (consecutive lanes -> consecutive si) ----
#pragma unroll
    for (int i = 0; i < 6; ++i) {
        int c  = tid + 256 * i;
        int si = c % 192;
        int d0 = (c / 192) * 8;
        int sc = min(max(s_base + si, 0), 511);
        half8 v = *(const half8*)(Vb + (abase + sc) * 256 + h * 64 + d0);
#pragma unroll
        for (int j = 0; j < 8; ++j) Vt[(d0 + j) * 200 + si] = v[j];
    }
    __syncthreads();

    const int md = *mdp, tw = *twp;
    const float md2 = (float)(md * md);

    // ---- S = Q K^T over 12 key tiles ----
    floatx4 S[12];
#pragma unroll
    for (int j = 0; j < 12; ++j) {
        half8 bk0 = *(const half8*)(&KPs[(j * 16 + l16) * 72 + quad * 8]);
        half8 bk1 = *(const half8*)(&KPs[(j * 16 + l16) * 72 + 32 + quad * 8]);
        floatx4 acc = {};
        acc = MFMA16(aq0, bk0, acc);
        acc = MFMA16(aq1, bk1, acc);
        int si = j * 16 + l16;
        int sr = s_base + si;
        int sc = min(max(sr, 0), 511);
        float2 kp = *(const float2*)(positions + (abase + sc) * 2);
        bool svalid = (sr >= 0) && (sr < 512);
#pragma unroll
        for (int r = 0; r < 4; ++r) {
            float dx = qpx[r] - kp.x, dy = qpy[r] - kp.y;
            float d2 = dx * dx + dy * dy;
            int dt = trow[r] - sr; dt = dt < 0 ? -dt : dt;
            bool ok = svalid && (d2 <= md2) && (dt <= tw);
            S[j][r] = ok ? acc[r] * 0.125f : -1e30f;   // scale = 1/sqrt(64)
        }
    }

    // ---- softmax (exact; quad shuffles) ----
    float minv[4];
#pragma unroll
    for (int r = 0; r < 4; ++r) {
        float m = -1e30f;
#pragma unroll
        for (int j = 0; j < 12; ++j) m = fmaxf(m, S[j][r]);
        m = fmaxf(m, __shfl_xor(m, 1));
        m = fmaxf(m, __shfl_xor(m, 2));
        m = fmaxf(m, __shfl_xor(m, 4));
        m = fmaxf(m, __shfl_xor(m, 8));
        float l = 0.f;
#pragma unroll
        for (int j = 0; j < 12; ++j) {
            float p = __expf(S[j][r] - m);
            S[j][r] = p;
            l += p;
        }
        l += __shfl_xor(l, 1);
        l += __shfl_xor(l, 2);
        l += __shfl_xor(l, 4);
        l += __shfl_xor(l, 8);
        minv[r] = 1.0f / l;
    }

    __syncthreads();   // all waves done reading Ks before Ps overwrites it

    // ---- write P into A-operand layout: row-major [16][200] per wave ----
    _Float16* Ps = KPs + wid * 16 * 200;
#pragma unroll
    for (int j = 0; j < 12; ++j)
#pragma unroll
        for (int r = 0; r < 4; ++r)
            Ps[(quad * 4 + r) * 200 + j * 16 + l16] = (_Float16)(S[j][r] * minv[r]);

    // ---- O = P V : M=16, K=192 (6 steps), N=64 (4 tiles) ----
    half8 af[6];
#pragma unroll
    for (int k = 0; k < 6; ++k)
        af[k] = *(const half8*)(&Ps[l16 * 200 + k * 32 + quad * 8]);
#pragma unroll
    for (int n = 0; n < 4; ++n) {
        floatx4 accO = {};
#pragma unroll
        for (int k = 0; k < 6; ++k) {
            half8 bv = *(const half8*)(&Vt[(n * 16 + l16) * 200 + k * 32 + quad * 8]);
            accO = MFMA16(af[k], bv, accO);
        }
#pragma unroll
        for (int r = 0; r < 4; ++r) {
            int row = q0 + wid * 16 + quad * 4 + r;
            attnb[(abase + row) * 256 + h * 64 + n * 16 + l16] = (_Float16)accO[r];
        }
    }
}

// ---------- launch ----------
extern "C" void kernel_launch(void* const* d_in, const int* in_sizes, int n_in,
                              void* d_out, int out_size, void* d_ws, size_t ws_size,
                              hipStream_t stream)
{
    const float* feat = (const float*)d_in[0];
    const float* pos  = (const float*)d_in[1];
    const float* Wq   = (const float*)d_in[2];
    const float* bq   = (const float*)d_in[3];
    const float* Wk   = (const float*)d_in[4];
    const float* bk   = (const float*)d_in[5];
    const float* Wv   = (const float*)d_in[6];
    const float* bv   = (const float*)d_in[7];
    const float* Wo   = (const float*)d_in[8];
    const float* bo   = (const float*)d_in[9];
    const int*   md   = (const int*)d_in[10];
    const int*   tw   = (const int*)d_in[11];
    float*       out  = (float*)d_out;

    _Float16* ws    = (_Float16*)d_ws;
    _Float16* featH = ws;                      // NFEAT halfs (reused as attnH)
    _Float16* WH    = featH + NFEAT;           // 4*NW halfs: wq, wk, wv, wo
    _Float16* Qb    = WH + 4 * NW;
    _Float16* Kb    = Qb + NFEAT;
    _Float16* Vb    = Kb + NFEAT;
    _Float16* attnH = featH;                   // features dead after qkv_gemm

    convert_kernel<<<8448, 256, 0, stream>>>(feat, Wq, Wk, Wv, Wo, ws);

    dim3 gqkv(6, 256);
    qkv_gemm<<<gqkv, 256, 0, stream>>>(featH, WH, bq, bk, bv, Qb, Kb, Vb);

    dim3 gattn(8, 4, 64);
    attn_kernel<<<gattn, 256, 0, stream>>>(Qb, Kb, Vb, pos, md, tw, attnH);

    dim3 gout(2, 256);
    out_gemm<<<gout, 256, 0, stream>>>(attnH, WH + 3 * (size_t)NW, bo, out);
}